// Round 18
// baseline (1011.576 us; speedup 1.0000x reference)
//
#include <hip/hip_runtime.h>
#include <math.h>

#define D_DIM 1024
#define N_COMP 4096
#define B_ROWS 16384
#define TOPK 8
#define NC_Q 16
#define NCAND 64
#define EPSV 1e-8f

typedef __bf16 bf16x8 __attribute__((ext_vector_type(8)));
typedef float f32x4 __attribute__((ext_vector_type(4)));

// ---------------- workspace layout (in float slots) ----------------
#define WS_MEAN  0         // 1024
#define WS_KNORM 1024      // 4096
#define WS_KNN   5120      // 4096*1024 f32 (bit-exact k_n, rescore input)
#define WS_KN16  4199424   // 4096*1024 bf16 (ushort) = 2097152 float slots
#define WS_CI    6296576   // candidate idx: 16384*64 ints
#define WS_TW    7345152   // softmax weights: 16384*8
#define WS_TI    7476224   // final idx: 16384*8 ints

__device__ __forceinline__ unsigned short bf16rne(float f) {
    unsigned int u = __float_as_uint(f);
    return (unsigned short)((u + 0x7FFFu + ((u >> 16) & 1u)) >> 16);
}

__device__ __forceinline__ void gload16(const void* g, void* l) {
    __builtin_amdgcn_global_load_lds(
        (const __attribute__((address_space(1))) void*)g,
        (__attribute__((address_space(3))) void*)l, 16, 0, 0);
}

__device__ __forceinline__ void nt_store4(const float4& v, float* p) {
    f32x4 x;
    x[0] = v.x; x[1] = v.y; x[2] = v.z; x[3] = v.w;
    __builtin_nontemporal_store(x, (f32x4*)p);
}

// ---------------- kernel A: np-faithful mean via LDS transpose --------------
__global__ void seqmean_kernel(const float* __restrict__ attn,
                               float* __restrict__ mean) {
    __shared__ float tile[128][65];
    const int tid = threadIdx.x;
    const int d0 = blockIdx.x * 64;
    const int c = tid & 63, r0 = tid >> 6;
    float acc = 0.f;
    for (int chunk = 0; chunk < 32; ++chunk) {
        const int base = chunk * 128;
        __syncthreads();
        #pragma unroll
        for (int rr = 0; rr < 32; ++rr) {
            int r = r0 * 32 + rr;
            tile[r][c] = attn[(size_t)(base + r) * D_DIM + d0 + c];
        }
        __syncthreads();
        if (tid < 64) {
            #pragma unroll 8
            for (int r = 0; r < 128; ++r)
                acc = __fadd_rn(acc, tile[r][tid]);
        }
    }
    if (tid < 64) mean[d0 + tid] = __fdiv_rn(acc, (float)N_COMP);
}

// ---------------- kernel B: np-faithful key norms, lane-parallel tree -------
__global__ void knorm_kernel(const float* __restrict__ keys,
                             float* __restrict__ knorm) {
    const int wave = threadIdx.x >> 6, lane = threadIdx.x & 63;
    const int n = blockIdx.x * 4 + wave;
    const float* x = keys + (size_t)n * D_DIM;
    const int l = lane & 15, g = lane >> 4;
    float lv0, lv1;
    {
        const float* xx = x + g * 128;
        float p[8];
        #pragma unroll
        for (int j = 0; j < 8; ++j) {
            float e = xx[16 * j + l];
            p[j] = __fmul_rn(e, e);
        }
        float t0 = __fadd_rn(p[0], p[1]), t1 = __fadd_rn(p[2], p[3]);
        float t2 = __fadd_rn(p[4], p[5]), t3 = __fadd_rn(p[6], p[7]);
        lv0 = __fadd_rn(__fadd_rn(t0, t1), __fadd_rn(t2, t3));
    }
    {
        const float* xx = x + (g + 4) * 128;
        float p[8];
        #pragma unroll
        for (int j = 0; j < 8; ++j) {
            float e = xx[16 * j + l];
            p[j] = __fmul_rn(e, e);
        }
        float t0 = __fadd_rn(p[0], p[1]), t1 = __fadd_rn(p[2], p[3]);
        float t2 = __fadd_rn(p[4], p[5]), t3 = __fadd_rn(p[6], p[7]);
        lv1 = __fadd_rn(__fadd_rn(t0, t1), __fadd_rn(t2, t3));
    }
    #pragma unroll
    for (int off = 8; off >= 1; off >>= 1) {
        lv0 = __fadd_rn(lv0, __shfl_down(lv0, off));
        lv1 = __fadd_rn(lv1, __shfl_down(lv1, off));
    }
    float L0 = __shfl(lv0, 0),  L1 = __shfl(lv0, 16),
          L2 = __shfl(lv0, 32), L3 = __shfl(lv0, 48);
    float L4 = __shfl(lv1, 0),  L5 = __shfl(lv1, 16),
          L6 = __shfl(lv1, 32), L7 = __shfl(lv1, 48);
    if (lane == 0) {
        float nk = __fadd_rn(
            __fadd_rn(__fadd_rn(L0, L1), __fadd_rn(L2, L3)),
            __fadd_rn(__fadd_rn(L4, L5), __fadd_rn(L6, L7)));
        knorm[n] = fmaxf(__fsqrt_rn(nk), EPSV);
    }
}

// ---------------- kernel C: knn f32 (frozen bits) + bf16 copy ---------------
__global__ void knn_kernel(const float* __restrict__ keys,
                           const float* __restrict__ knorm,
                           float* __restrict__ knn,
                           unsigned short* __restrict__ kn16) {
    int n = blockIdx.x;
    float kn = knorm[n];
    int d = threadIdx.x * 4;
    const float* row = keys + (size_t)n * D_DIM + d;
    float* orow = knn + (size_t)n * D_DIM + d;
    unsigned short* o16 = kn16 + (size_t)n * D_DIM + d;
    float r0 = __fdiv_rn(row[0], kn);
    float r1 = __fdiv_rn(row[1], kn);
    float r2 = __fdiv_rn(row[2], kn);
    float r3 = __fdiv_rn(row[3], kn);
    orow[0] = r0; orow[1] = r1; orow[2] = r2; orow[3] = r3;
    o16[0] = bf16rne(r0); o16[1] = bf16rne(r1);
    o16[2] = bf16rne(r2); o16[3] = bf16rne(r3);
}

// ---------------- kernel C2: aq16 = bf16(q * mean), precomputed -------------
__global__ void aq16_kernel(const float* __restrict__ q,
                            const float* __restrict__ mean,
                            unsigned short* __restrict__ aq16) {
    size_t i = ((size_t)blockIdx.x * 256 + threadIdx.x) * 8;
    int d = (int)(i & (D_DIM - 1));
    float4 a0 = *(const float4*)(q + i);
    float4 a1 = *(const float4*)(q + i + 4);
    float4 m0 = *(const float4*)(mean + d);
    float4 m1 = *(const float4*)(mean + d + 4);
    uint4 pk;
    pk.x = (unsigned)bf16rne(a0.x * m0.x) | ((unsigned)bf16rne(a0.y * m0.y) << 16);
    pk.y = (unsigned)bf16rne(a0.z * m0.z) | ((unsigned)bf16rne(a0.w * m0.w) << 16);
    pk.z = (unsigned)bf16rne(a1.x * m1.x) | ((unsigned)bf16rne(a1.y * m1.y) << 16);
    pk.w = (unsigned)bf16rne(a1.z * m1.z) | ((unsigned)bf16rne(a1.w * m1.w) << 16);
    *(uint4*)(aq16 + i) = pk;
}

// ---------------- kernel D: MFMA bf16 GEMM + per-quarter top-16 v6 ----------
// R11 main loop (untouched). Epilogue: 512 threads = 128 rows x 4 slices of
// 32 cols (vs 128x2x64) — same scalar scan body, 2x parallelism, half the
// chain. Final: 4-way sorted-list merge per row (IM as ushort, ids < 4096).
__global__ __launch_bounds__(512, 4) void simtop_mfma(
    const unsigned short* __restrict__ aq16,
    const unsigned short* __restrict__ kn16,
    int* __restrict__ candi, float* __restrict__ candv) {
    __shared__ __align__(16) char RAW[49152];
    uint4* A4 = (uint4*)RAW;               // [128 rows][8 slots] 16KB
    uint4* B4 = (uint4*)(RAW + 16384);     // [256 cols][8 slots] 32KB
    float* SIM = (float*)RAW;              // [64][129] overlay (epilogue)
    float* VM  = (float*)RAW;              // [512 lists][16] overlay 32KB
    unsigned short* IM = (unsigned short*)(RAW + 32768); // [512][16] 16KB

    const int tid = threadIdx.x;
    const int lane = tid & 63;
    const int wid = tid >> 6;
    const int wr = wid >> 2, wc = wid & 3;
    const int l15 = lane & 15, l4 = lane >> 4;
    const int rb = blockIdx.x >> 2;
    const int qq = blockIdx.x & 3;
    const int row0 = rb * 128;
    const int colQ = qq * 1024;
    const int srow2 = tid >> 2;            // owned row 0..127
    const int slice = tid & 3;             // 32-col slice

    float v[NC_Q]; int ix[NC_Q];
    #pragma unroll
    for (int s = 0; s < NC_Q; ++s) { v[s] = -1e30f; ix[s] = 0; }

    for (int ct = 0; ct < 4; ++ct) {
        const int col0 = colQ + ct * 256;
        f32x4 acc[4][4];
        #pragma unroll
        for (int i = 0; i < 4; ++i)
            #pragma unroll
            for (int j = 0; j < 4; ++j) {
                acc[i][j][0] = 0.f; acc[i][j][1] = 0.f;
                acc[i][j][2] = 0.f; acc[i][j][3] = 0.f;
            }

        for (int kt = 0; kt < 16; ++kt) {
            const int k0 = kt * 64;
            __syncthreads();
            #pragma unroll
            for (int c = 0; c < 2; ++c) {
                int unit = c * 512 + tid;
                int r = unit >> 3, j = unit & 7;
                gload16(aq16 + (size_t)(row0 + r) * D_DIM + k0 + (j ^ (r & 7)) * 8,
                        (char*)A4 + unit * 16);
            }
            #pragma unroll
            for (int c = 0; c < 4; ++c) {
                int unit = c * 512 + tid;
                int r = unit >> 3, j = unit & 7;
                gload16(kn16 + (size_t)(col0 + r) * D_DIM + k0 + (j ^ (r & 7)) * 8,
                        (char*)B4 + unit * 16);
            }
            __syncthreads();
            #pragma unroll
            for (int kk = 0; kk < 2; ++kk) {
                bf16x8 af[4], bfv[4];
                #pragma unroll
                for (int f = 0; f < 4; ++f) {
                    int rowa = wr * 64 + f * 16 + l15;
                    int slot = kk * 4 + l4;
                    af[f] = __builtin_bit_cast(bf16x8,
                              A4[rowa * 8 + (slot ^ (rowa & 7))]);
                    int rowb = wc * 64 + f * 16 + l15;
                    bfv[f] = __builtin_bit_cast(bf16x8,
                              B4[rowb * 8 + (slot ^ (rowb & 7))]);
                }
                #pragma unroll
                for (int i = 0; i < 4; ++i)
                    #pragma unroll
                    for (int j = 0; j < 4; ++j)
                        acc[i][j] = __builtin_amdgcn_mfma_f32_16x16x32_bf16(
                            af[i], bfv[j], acc[i][j], 0, 0, 0);
            }
        }
        // epilogue: 4 phases; writers as R11; all matching-row threads scan
        #pragma unroll 1
        for (int p = 0; p < 4; ++p) {
            __syncthreads();
            if (wr == (p >> 1) && (wc >> 1) == (p & 1)) {
                #pragma unroll
                for (int i = 0; i < 4; ++i)
                    #pragma unroll
                    for (int j = 0; j < 4; ++j)
                        #pragma unroll
                        for (int rg = 0; rg < 4; ++rg)
                            SIM[(i * 16 + l4 * 4 + rg) * 129 +
                                (wc & 1) * 64 + j * 16 + l15] = acc[i][j][rg];
            }
            __syncthreads();
            if ((srow2 >> 6) == (p >> 1)) {
                const float* rp = SIM + (srow2 & 63) * 129 + slice * 32;
                const int gbase = col0 + (p & 1) * 128 + slice * 32;
                #pragma unroll 1
                for (int cc = 0; cc < 32; ++cc) {
                    float cv = rp[cc];
                    if (cv > v[NC_Q - 1]) {
                        v[NC_Q - 1] = cv; ix[NC_Q - 1] = gbase + cc;
                        #pragma unroll
                        for (int s = NC_Q - 1; s > 0; --s)
                            if (v[s] > v[s - 1]) {
                                float tv = v[s]; v[s] = v[s - 1]; v[s - 1] = tv;
                                int ti = ix[s]; ix[s] = ix[s - 1]; ix[s - 1] = ti;
                            }
                    }
                }
            }
        }
    }
    // ---- final: lists -> LDS, 4-way merge per row -> top-16/quarter ----
    __syncthreads();
    {
        float* mv = VM + tid * 16;
        unsigned short* mi = IM + tid * 16;
        #pragma unroll
        for (int s = 0; s < NC_Q; ++s) {
            mv[s] = v[s];
            mi[s] = (unsigned short)ix[s];
        }
    }
    __syncthreads();
    if (tid < 128) {
        const float* b0 = VM + (size_t)(tid * 4 + 0) * 16;
        const float* b1 = VM + (size_t)(tid * 4 + 1) * 16;
        const float* b2 = VM + (size_t)(tid * 4 + 2) * 16;
        const float* b3 = VM + (size_t)(tid * 4 + 3) * 16;
        const unsigned short* m0 = IM + (size_t)(tid * 4 + 0) * 16;
        const unsigned short* m1 = IM + (size_t)(tid * 4 + 1) * 16;
        const unsigned short* m2 = IM + (size_t)(tid * 4 + 2) * 16;
        const unsigned short* m3 = IM + (size_t)(tid * 4 + 3) * 16;
        int h0 = 0, h1 = 0, h2 = 0, h3 = 0;
        size_t obase = (size_t)(row0 + tid) * NCAND + qq * 16;
        #pragma unroll 1
        for (int s = 0; s < NC_Q; ++s) {
            float v0 = (h0 < 16) ? b0[h0] : -3e38f;
            float v1 = (h1 < 16) ? b1[h1] : -3e38f;
            float v2 = (h2 < 16) ? b2[h2] : -3e38f;
            float v3 = (h3 < 16) ? b3[h3] : -3e38f;
            int which = 0; float bv = v0;
            if (v1 > bv) { bv = v1; which = 1; }
            if (v2 > bv) { bv = v2; which = 2; }
            if (v3 > bv) { bv = v3; which = 3; }
            int id;
            if (which == 0)      { id = m0[h0]; ++h0; }
            else if (which == 1) { id = m1[h1]; ++h1; }
            else if (which == 2) { id = m2[h2]; ++h2; }
            else                 { id = m3[h3]; ++h3; }
            candi[obase + s] = id;
            candv[obase + s] = bv;
        }
    }
}

// ---------------- kernel E: sparse bit-faithful KC=320 rescore (frozen) -----
__global__ __launch_bounds__(256) void rescore_kernel(
    const float* __restrict__ q, const float* __restrict__ knn,
    const float* __restrict__ mean, const int* __restrict__ candi,
    const float* __restrict__ candv,
    float* __restrict__ topw, int* __restrict__ topi) {
    __shared__ float anbuf[D_DIM];
    __shared__ float vbuf[NCAND];
    __shared__ int ibuf[NCAND];
    __shared__ int selid[NCAND];
    __shared__ float snq;
    __shared__ int m_s;
    const int tid = threadIdx.x;
    const int wave = tid >> 6, lane = tid & 63;
    const int b = blockIdx.x;
    const float* qr = q + (size_t)b * D_DIM;

    if (wave == 0) {
        const int l = lane & 15, g = lane >> 4;
        float lv0, lv1;
        {
            const float* x = qr + g * 128;
            const float* m = mean + g * 128;
            float p[8];
            #pragma unroll
            for (int j = 0; j < 8; ++j) {
                float e = __fmul_rn(x[16 * j + l], m[16 * j + l]);
                p[j] = __fmul_rn(e, e);
            }
            float t0 = __fadd_rn(p[0], p[1]), t1 = __fadd_rn(p[2], p[3]);
            float t2 = __fadd_rn(p[4], p[5]), t3 = __fadd_rn(p[6], p[7]);
            lv0 = __fadd_rn(__fadd_rn(t0, t1), __fadd_rn(t2, t3));
        }
        {
            const float* x = qr + (g + 4) * 128;
            const float* m = mean + (g + 4) * 128;
            float p[8];
            #pragma unroll
            for (int j = 0; j < 8; ++j) {
                float e = __fmul_rn(x[16 * j + l], m[16 * j + l]);
                p[j] = __fmul_rn(e, e);
            }
            float t0 = __fadd_rn(p[0], p[1]), t1 = __fadd_rn(p[2], p[3]);
            float t2 = __fadd_rn(p[4], p[5]), t3 = __fadd_rn(p[6], p[7]);
            lv1 = __fadd_rn(__fadd_rn(t0, t1), __fadd_rn(t2, t3));
        }
        #pragma unroll
        for (int off = 8; off >= 1; off >>= 1) {
            lv0 = __fadd_rn(lv0, __shfl_down(lv0, off));
            lv1 = __fadd_rn(lv1, __shfl_down(lv1, off));
        }
        float L0 = __shfl(lv0, 0),  L1 = __shfl(lv0, 16),
              L2 = __shfl(lv0, 32), L3 = __shfl(lv0, 48);
        float L4 = __shfl(lv1, 0),  L5 = __shfl(lv1, 16),
              L6 = __shfl(lv1, 32), L7 = __shfl(lv1, 48);
        if (lane == 0) {
            float nq = __fadd_rn(
                __fadd_rn(__fadd_rn(L0, L1), __fadd_rn(L2, L3)),
                __fadd_rn(__fadd_rn(L4, L5), __fadd_rn(L6, L7)));
            snq = fmaxf(__fsqrt_rn(nq), EPSV);
        }
    }
    __syncthreads();
    const float nqd = snq;

    {
        int d0 = tid * 4;
        float4 qv = *(const float4*)(qr + d0);
        float4 mv = *(const float4*)(mean + d0);
        anbuf[d0 + 0] = __fdiv_rn(__fmul_rn(qv.x, mv.x), nqd);
        anbuf[d0 + 1] = __fdiv_rn(__fmul_rn(qv.y, mv.y), nqd);
        anbuf[d0 + 2] = __fdiv_rn(__fmul_rn(qv.z, mv.z), nqd);
        anbuf[d0 + 3] = __fdiv_rn(__fmul_rn(qv.w, mv.w), nqd);
    }

    if (wave == 1) {
        float av = candv[(size_t)b * NCAND + lane];
        int aid = candi[(size_t)b * NCAND + lane];
        float t8;
        {
            float vv = av; int vid = aid;
            #pragma unroll
            for (int s = 0; s < TOPK; ++s) {
                float bv = vv; int bid = vid;
                #pragma unroll
                for (int off = 32; off >= 1; off >>= 1) {
                    float ov = __shfl_xor(bv, off);
                    int oid = __shfl_xor(bid, off);
                    if (ov > bv || (ov == bv && oid < bid)) { bv = ov; bid = oid; }
                }
                t8 = bv;
                if (vid == bid) vv = -1e30f;
            }
        }
        float thr = t8 - 0.003f * nqd;
        bool sel = (av >= thr);
        unsigned long long mk = __ballot(sel);
        int pos = __popcll(mk & ((1ull << lane) - 1ull));
        if (sel) selid[pos] = aid;
        if (lane == 0) m_s = (int)__popcll(mk);
    }
    __syncthreads();
    const int m = m_s;

    {
        const int s = tid >> 2, chunk = tid & 3;
        if (s < m) {
            const int id = selid[s];
            const int start = chunk * 320;
            const int n4 = (chunk == 3) ? 16 : 80;
            const float4* k4 = (const float4*)(knn + (size_t)id * D_DIM + start);
            const float4* a4 = (const float4*)(anbuf + start);
            float acc = 0.f;
            #pragma unroll 4
            for (int t = 0; t < n4; ++t) {
                float4 kv = k4[t];
                float4 av4 = a4[t];
                acc = __fmaf_rn(av4.x, kv.x, acc);
                acc = __fmaf_rn(av4.y, kv.y, acc);
                acc = __fmaf_rn(av4.z, kv.z, acc);
                acc = __fmaf_rn(av4.w, kv.w, acc);
            }
            float c2 = __shfl_down(acc, 1);
            float c3 = __shfl_down(acc, 2);
            float c4 = __shfl_down(acc, 3);
            if (chunk == 0) {
                vbuf[s] = __fadd_rn(__fadd_rn(__fadd_rn(acc, c2), c3), c4);
                ibuf[s] = id;
            }
        }
    }
    __syncthreads();

    if (wave == 0) {
        float v = (lane < m) ? vbuf[lane] : -3e38f;
        int id = (lane < m) ? ibuf[lane] : 0x7fffffff;
        float sv[TOPK]; int si[TOPK];
        #pragma unroll
        for (int s = 0; s < TOPK; ++s) {
            float bv = v; int bid = id;
            #pragma unroll
            for (int off = 32; off >= 1; off >>= 1) {
                float ov = __shfl_xor(bv, off);
                int oid = __shfl_xor(bid, off);
                if (ov > bv || (ov == bv && oid < bid)) { bv = ov; bid = oid; }
            }
            sv[s] = bv; si[s] = bid;
            if (id == bid) v = -3e38f;
        }
        if (lane == 0) {
            float mx = sv[0];
            float w[TOPK];
            float ssum = 0.f;
            #pragma unroll
            for (int k = 0; k < TOPK; ++k) { w[k] = expf(sv[k] - mx); ssum += w[k]; }
            float rs = 1.0f / ssum;
            #pragma unroll
            for (int k = 0; k < TOPK; ++k) {
                topw[b * TOPK + k] = w[k] * rs;
                topi[b * TOPK + k] = si[k];
            }
        }
    }
}

// ---------------- kernel F: weighted gather + outputs (nt stores) -----------
__global__ void output_kernel(const float* __restrict__ topw,
                              const int* __restrict__ topi,
                              const float* __restrict__ prompts,
                              const float* __restrict__ keys,
                              float* __restrict__ out) {
    int b = blockIdx.x;
    float w[TOPK];
    int id[TOPK];
    #pragma unroll
    for (int k = 0; k < TOPK; ++k) {
        w[k] = topw[b * TOPK + k];
        id[k] = topi[b * TOPK + k];
    }

    const size_t OFF1 = (size_t)B_ROWS * D_DIM;
    const size_t OFF2 = OFF1 + (size_t)B_ROWS * TOPK;

    if (threadIdx.x < TOPK)
        out[OFF1 + (size_t)b * TOPK + threadIdx.x] = (float)id[threadIdx.x];

    int d0 = threadIdx.x * 4;
    float4 acc; acc.x = acc.y = acc.z = acc.w = 0.f;
    #pragma unroll
    for (int k = 0; k < TOPK; ++k) {
        const float* pr = prompts + (size_t)id[k] * D_DIM + d0;
        float4 pv = *(const float4*)pr;
        acc.x += w[k] * pv.x; acc.y += w[k] * pv.y;
        acc.z += w[k] * pv.z; acc.w += w[k] * pv.w;
        const float* kr = keys + (size_t)id[k] * D_DIM + d0;
        float4 kv = *(const float4*)kr;
        nt_store4(kv, out + OFF2 + ((size_t)b * TOPK + k) * D_DIM + d0);
    }
    nt_store4(acc, out + (size_t)b * D_DIM + d0);
}

// ---------------- launch ----------------
extern "C" void kernel_launch(void* const* d_in, const int* in_sizes, int n_in,
                              void* d_out, int out_size, void* d_ws, size_t ws_size,
                              hipStream_t stream) {
    const float* query   = (const float*)d_in[0];
    const float* prompts = (const float*)d_in[1];
    const float* keys    = (const float*)d_in[2];
    const float* attn    = (const float*)d_in[3];
    float* ws = (float*)d_ws;
    float* out = (float*)d_out;

    float* mean  = ws + WS_MEAN;
    float* knorm = ws + WS_KNORM;
    float* knn   = ws + WS_KNN;
    unsigned short* kn16 = (unsigned short*)(ws + WS_KN16);
    int*   candi = (int*)(ws + WS_CI);
    float* topw  = ws + WS_TW;
    int*   topi  = (int*)(ws + WS_TI);
    float* outscratch = out + (size_t)B_ROWS * D_DIM + (size_t)B_ROWS * TOPK;
    unsigned short* aq16 = (unsigned short*)outscratch;
    float* candv = outscratch + 8388608;

    seqmean_kernel<<<16, 256, 0, stream>>>(attn, mean);
    knorm_kernel<<<N_COMP / 4, 256, 0, stream>>>(keys, knorm);
    knn_kernel<<<N_COMP, 256, 0, stream>>>(keys, knorm, knn, kn16);
    aq16_kernel<<<8192, 256, 0, stream>>>(query, mean, aq16);
    simtop_mfma<<<512, 512, 0, stream>>>(aq16, kn16, candi, candv);
    rescore_kernel<<<B_ROWS, 256, 0, stream>>>(query, knn, mean, candi, candv,
                                               topw, topi);
    output_kernel<<<B_ROWS, 256, 0, stream>>>(topw, topi, prompts, keys, out);
}

// Round 19
// 906.734 us; speedup vs baseline: 1.1156x; 1.1156x over previous
//
#include <hip/hip_runtime.h>
#include <math.h>

#define D_DIM 1024
#define N_COMP 4096
#define B_ROWS 16384
#define TOPK 8
#define NC_Q 16
#define NCAND 64
#define EPSV 1e-8f

typedef __bf16 bf16x8 __attribute__((ext_vector_type(8)));
typedef float f32x4 __attribute__((ext_vector_type(4)));

// ---------------- workspace layout (in float slots) ----------------
#define WS_MEAN  0         // 1024
#define WS_KNORM 1024      // 4096
#define WS_KNN   5120      // 4096*1024 f32 (bit-exact k_n, rescore input)
#define WS_KN16  4199424   // 4096*1024 bf16 (ushort) = 2097152 float slots
#define WS_CI    6296576   // candidate idx: 16384*64 ints
#define WS_TW    7345152   // softmax weights: 16384*8
#define WS_TI    7476224   // final idx: 16384*8 ints

__device__ __forceinline__ unsigned short bf16rne(float f) {
    unsigned int u = __float_as_uint(f);
    return (unsigned short)((u + 0x7FFFu + ((u >> 16) & 1u)) >> 16);
}

__device__ __forceinline__ void gload16(const void* g, void* l) {
    __builtin_amdgcn_global_load_lds(
        (const __attribute__((address_space(1))) void*)g,
        (__attribute__((address_space(3))) void*)l, 16, 0, 0);
}

__device__ __forceinline__ void nt_store4(const float4& v, float* p) {
    f32x4 x;
    x[0] = v.x; x[1] = v.y; x[2] = v.z; x[3] = v.w;
    __builtin_nontemporal_store(x, (f32x4*)p);
}

// ---------------- kernel A: np-faithful mean via LDS transpose --------------
__global__ void seqmean_kernel(const float* __restrict__ attn,
                               float* __restrict__ mean) {
    __shared__ float tile[128][65];
    const int tid = threadIdx.x;
    const int d0 = blockIdx.x * 64;
    const int c = tid & 63, r0 = tid >> 6;
    float acc = 0.f;
    for (int chunk = 0; chunk < 32; ++chunk) {
        const int base = chunk * 128;
        __syncthreads();
        #pragma unroll
        for (int rr = 0; rr < 32; ++rr) {
            int r = r0 * 32 + rr;
            tile[r][c] = attn[(size_t)(base + r) * D_DIM + d0 + c];
        }
        __syncthreads();
        if (tid < 64) {
            #pragma unroll 8
            for (int r = 0; r < 128; ++r)
                acc = __fadd_rn(acc, tile[r][tid]);
        }
    }
    if (tid < 64) mean[d0 + tid] = __fdiv_rn(acc, (float)N_COMP);
}

// ---------------- kernel B: np-faithful key norms, lane-parallel tree -------
__global__ void knorm_kernel(const float* __restrict__ keys,
                             float* __restrict__ knorm) {
    const int wave = threadIdx.x >> 6, lane = threadIdx.x & 63;
    const int n = blockIdx.x * 4 + wave;
    const float* x = keys + (size_t)n * D_DIM;
    const int l = lane & 15, g = lane >> 4;
    float lv0, lv1;
    {
        const float* xx = x + g * 128;
        float p[8];
        #pragma unroll
        for (int j = 0; j < 8; ++j) {
            float e = xx[16 * j + l];
            p[j] = __fmul_rn(e, e);
        }
        float t0 = __fadd_rn(p[0], p[1]), t1 = __fadd_rn(p[2], p[3]);
        float t2 = __fadd_rn(p[4], p[5]), t3 = __fadd_rn(p[6], p[7]);
        lv0 = __fadd_rn(__fadd_rn(t0, t1), __fadd_rn(t2, t3));
    }
    {
        const float* xx = x + (g + 4) * 128;
        float p[8];
        #pragma unroll
        for (int j = 0; j < 8; ++j) {
            float e = xx[16 * j + l];
            p[j] = __fmul_rn(e, e);
        }
        float t0 = __fadd_rn(p[0], p[1]), t1 = __fadd_rn(p[2], p[3]);
        float t2 = __fadd_rn(p[4], p[5]), t3 = __fadd_rn(p[6], p[7]);
        lv1 = __fadd_rn(__fadd_rn(t0, t1), __fadd_rn(t2, t3));
    }
    #pragma unroll
    for (int off = 8; off >= 1; off >>= 1) {
        lv0 = __fadd_rn(lv0, __shfl_down(lv0, off));
        lv1 = __fadd_rn(lv1, __shfl_down(lv1, off));
    }
    float L0 = __shfl(lv0, 0),  L1 = __shfl(lv0, 16),
          L2 = __shfl(lv0, 32), L3 = __shfl(lv0, 48);
    float L4 = __shfl(lv1, 0),  L5 = __shfl(lv1, 16),
          L6 = __shfl(lv1, 32), L7 = __shfl(lv1, 48);
    if (lane == 0) {
        float nk = __fadd_rn(
            __fadd_rn(__fadd_rn(L0, L1), __fadd_rn(L2, L3)),
            __fadd_rn(__fadd_rn(L4, L5), __fadd_rn(L6, L7)));
        knorm[n] = fmaxf(__fsqrt_rn(nk), EPSV);
    }
}

// ---------------- kernel C: knn f32 (frozen bits) + bf16 copy ---------------
__global__ void knn_kernel(const float* __restrict__ keys,
                           const float* __restrict__ knorm,
                           float* __restrict__ knn,
                           unsigned short* __restrict__ kn16) {
    int n = blockIdx.x;
    float kn = knorm[n];
    int d = threadIdx.x * 4;
    const float* row = keys + (size_t)n * D_DIM + d;
    float* orow = knn + (size_t)n * D_DIM + d;
    unsigned short* o16 = kn16 + (size_t)n * D_DIM + d;
    float r0 = __fdiv_rn(row[0], kn);
    float r1 = __fdiv_rn(row[1], kn);
    float r2 = __fdiv_rn(row[2], kn);
    float r3 = __fdiv_rn(row[3], kn);
    orow[0] = r0; orow[1] = r1; orow[2] = r2; orow[3] = r3;
    o16[0] = bf16rne(r0); o16[1] = bf16rne(r1);
    o16[2] = bf16rne(r2); o16[3] = bf16rne(r3);
}

// ---------------- kernel C2: aq16 = bf16(q * mean), precomputed -------------
__global__ void aq16_kernel(const float* __restrict__ q,
                            const float* __restrict__ mean,
                            unsigned short* __restrict__ aq16) {
    size_t i = ((size_t)blockIdx.x * 256 + threadIdx.x) * 8;
    int d = (int)(i & (D_DIM - 1));
    float4 a0 = *(const float4*)(q + i);
    float4 a1 = *(const float4*)(q + i + 4);
    float4 m0 = *(const float4*)(mean + d);
    float4 m1 = *(const float4*)(mean + d + 4);
    uint4 pk;
    pk.x = (unsigned)bf16rne(a0.x * m0.x) | ((unsigned)bf16rne(a0.y * m0.y) << 16);
    pk.y = (unsigned)bf16rne(a0.z * m0.z) | ((unsigned)bf16rne(a0.w * m0.w) << 16);
    pk.z = (unsigned)bf16rne(a1.x * m1.x) | ((unsigned)bf16rne(a1.y * m1.y) << 16);
    pk.w = (unsigned)bf16rne(a1.z * m1.z) | ((unsigned)bf16rne(a1.w * m1.w) << 16);
    *(uint4*)(aq16 + i) = pk;
}

// ---------------- kernel D: MFMA bf16 GEMM + per-quarter top-16 -------------
// R11/R15-exact artifact (profiled 481 us): 128 rows x 1024 quarter,
// 4 col-tiles of 256, BK=64, 8 waves, global_load_lds w=16 XOR-swizzled.
__global__ __launch_bounds__(512, 4) void simtop_mfma(
    const unsigned short* __restrict__ aq16,
    const unsigned short* __restrict__ kn16,
    int* __restrict__ candi, float* __restrict__ candv) {
    __shared__ __align__(16) char RAW[49152];
    uint4* A4 = (uint4*)RAW;               // [128 rows][8 slots] 16KB
    uint4* B4 = (uint4*)(RAW + 16384);     // [256 cols][8 slots] 32KB
    float* SIM = (float*)RAW;              // [64][129] overlay (epilogue)
    float* VM  = (float*)RAW;              // [256][16] overlay (merge)
    int*   IM  = (int*)(RAW + 16384);      // [256][16]

    const int tid = threadIdx.x;
    const int lane = tid & 63;
    const int wid = tid >> 6;
    const int wr = wid >> 2, wc = wid & 3;
    const int l15 = lane & 15, l4 = lane >> 4;
    const int rb = blockIdx.x >> 2;
    const int qq = blockIdx.x & 3;
    const int row0 = rb * 128;
    const int colQ = qq * 1024;
    const int srow = tid & 127;
    const int sstripe = (tid >> 7) & 1;

    float v[NC_Q]; int ix[NC_Q];
    #pragma unroll
    for (int s = 0; s < NC_Q; ++s) { v[s] = -1e30f; ix[s] = 0; }

    for (int ct = 0; ct < 4; ++ct) {
        const int col0 = colQ + ct * 256;
        f32x4 acc[4][4];
        #pragma unroll
        for (int i = 0; i < 4; ++i)
            #pragma unroll
            for (int j = 0; j < 4; ++j) {
                acc[i][j][0] = 0.f; acc[i][j][1] = 0.f;
                acc[i][j][2] = 0.f; acc[i][j][3] = 0.f;
            }

        for (int kt = 0; kt < 16; ++kt) {
            const int k0 = kt * 64;
            __syncthreads();
            #pragma unroll
            for (int c = 0; c < 2; ++c) {
                int unit = c * 512 + tid;
                int r = unit >> 3, j = unit & 7;
                gload16(aq16 + (size_t)(row0 + r) * D_DIM + k0 + (j ^ (r & 7)) * 8,
                        (char*)A4 + unit * 16);
            }
            #pragma unroll
            for (int c = 0; c < 4; ++c) {
                int unit = c * 512 + tid;
                int r = unit >> 3, j = unit & 7;
                gload16(kn16 + (size_t)(col0 + r) * D_DIM + k0 + (j ^ (r & 7)) * 8,
                        (char*)B4 + unit * 16);
            }
            __syncthreads();
            #pragma unroll
            for (int kk = 0; kk < 2; ++kk) {
                bf16x8 af[4], bfv[4];
                #pragma unroll
                for (int f = 0; f < 4; ++f) {
                    int rowa = wr * 64 + f * 16 + l15;
                    int slot = kk * 4 + l4;
                    af[f] = __builtin_bit_cast(bf16x8,
                              A4[rowa * 8 + (slot ^ (rowa & 7))]);
                    int rowb = wc * 64 + f * 16 + l15;
                    bfv[f] = __builtin_bit_cast(bf16x8,
                              B4[rowb * 8 + (slot ^ (rowb & 7))]);
                }
                #pragma unroll
                for (int i = 0; i < 4; ++i)
                    #pragma unroll
                    for (int j = 0; j < 4; ++j)
                        acc[i][j] = __builtin_amdgcn_mfma_f32_16x16x32_bf16(
                            af[i], bfv[j], acc[i][j], 0, 0, 0);
            }
        }
        #pragma unroll 1
        for (int p = 0; p < 4; ++p) {
            __syncthreads();
            if (wr == (p >> 1) && (wc >> 1) == (p & 1)) {
                #pragma unroll
                for (int i = 0; i < 4; ++i)
                    #pragma unroll
                    for (int j = 0; j < 4; ++j)
                        #pragma unroll
                        for (int rg = 0; rg < 4; ++rg)
                            SIM[(i * 16 + l4 * 4 + rg) * 129 +
                                (wc & 1) * 64 + j * 16 + l15] = acc[i][j][rg];
            }
            __syncthreads();
            if (tid < 256 && (srow >> 6) == (p >> 1)) {
                const float* rp = SIM + (srow & 63) * 129 + sstripe * 64;
                const int gbase = col0 + (p & 1) * 128 + sstripe * 64;
                #pragma unroll 1
                for (int cc = 0; cc < 64; ++cc) {
                    float cv = rp[cc];
                    if (cv > v[NC_Q - 1]) {
                        v[NC_Q - 1] = cv; ix[NC_Q - 1] = gbase + cc;
                        #pragma unroll
                        for (int s = NC_Q - 1; s > 0; --s)
                            if (v[s] > v[s - 1]) {
                                float tv = v[s]; v[s] = v[s - 1]; v[s - 1] = tv;
                                int ti = ix[s]; ix[s] = ix[s - 1]; ix[s - 1] = ti;
                            }
                    }
                }
            }
        }
    }
    __syncthreads();
    if (tid < 256) {
        #pragma unroll
        for (int s = 0; s < NC_Q; ++s) {
            VM[tid * 16 + s] = v[s];
            IM[tid * 16 + s] = ix[s];
        }
    }
    __syncthreads();
    if (tid < 128) {
        int ia = 0, ib = 0;
        size_t obase = (size_t)(row0 + tid) * NCAND + qq * 16;
        #pragma unroll 1
        for (int s = 0; s < NC_Q; ++s) {
            float va = (ia < 16) ? VM[tid * 16 + ia] : -3e38f;
            float vb = (ib < 16) ? VM[(tid + 128) * 16 + ib] : -3e38f;
            int id; float vv;
            if (va >= vb) { id = IM[tid * 16 + ia]; vv = va; ++ia; }
            else          { id = IM[(tid + 128) * 16 + ib]; vv = vb; ++ib; }
            candi[obase + s] = id;
            candv[obase + s] = vv;
        }
    }
}

// ---------------- kernel E: sparse bit-faithful KC=320 rescore (frozen) -----
__global__ __launch_bounds__(256) void rescore_kernel(
    const float* __restrict__ q, const float* __restrict__ knn,
    const float* __restrict__ mean, const int* __restrict__ candi,
    const float* __restrict__ candv,
    float* __restrict__ topw, int* __restrict__ topi) {
    __shared__ float anbuf[D_DIM];
    __shared__ float vbuf[NCAND];
    __shared__ int ibuf[NCAND];
    __shared__ int selid[NCAND];
    __shared__ float snq;
    __shared__ int m_s;
    const int tid = threadIdx.x;
    const int wave = tid >> 6, lane = tid & 63;
    const int b = blockIdx.x;
    const float* qr = q + (size_t)b * D_DIM;

    if (wave == 0) {
        const int l = lane & 15, g = lane >> 4;
        float lv0, lv1;
        {
            const float* x = qr + g * 128;
            const float* m = mean + g * 128;
            float p[8];
            #pragma unroll
            for (int j = 0; j < 8; ++j) {
                float e = __fmul_rn(x[16 * j + l], m[16 * j + l]);
                p[j] = __fmul_rn(e, e);
            }
            float t0 = __fadd_rn(p[0], p[1]), t1 = __fadd_rn(p[2], p[3]);
            float t2 = __fadd_rn(p[4], p[5]), t3 = __fadd_rn(p[6], p[7]);
            lv0 = __fadd_rn(__fadd_rn(t0, t1), __fadd_rn(t2, t3));
        }
        {
            const float* x = qr + (g + 4) * 128;
            const float* m = mean + (g + 4) * 128;
            float p[8];
            #pragma unroll
            for (int j = 0; j < 8; ++j) {
                float e = __fmul_rn(x[16 * j + l], m[16 * j + l]);
                p[j] = __fmul_rn(e, e);
            }
            float t0 = __fadd_rn(p[0], p[1]), t1 = __fadd_rn(p[2], p[3]);
            float t2 = __fadd_rn(p[4], p[5]), t3 = __fadd_rn(p[6], p[7]);
            lv1 = __fadd_rn(__fadd_rn(t0, t1), __fadd_rn(t2, t3));
        }
        #pragma unroll
        for (int off = 8; off >= 1; off >>= 1) {
            lv0 = __fadd_rn(lv0, __shfl_down(lv0, off));
            lv1 = __fadd_rn(lv1, __shfl_down(lv1, off));
        }
        float L0 = __shfl(lv0, 0),  L1 = __shfl(lv0, 16),
              L2 = __shfl(lv0, 32), L3 = __shfl(lv0, 48);
        float L4 = __shfl(lv1, 0),  L5 = __shfl(lv1, 16),
              L6 = __shfl(lv1, 32), L7 = __shfl(lv1, 48);
        if (lane == 0) {
            float nq = __fadd_rn(
                __fadd_rn(__fadd_rn(L0, L1), __fadd_rn(L2, L3)),
                __fadd_rn(__fadd_rn(L4, L5), __fadd_rn(L6, L7)));
            snq = fmaxf(__fsqrt_rn(nq), EPSV);
        }
    }
    __syncthreads();
    const float nqd = snq;

    {
        int d0 = tid * 4;
        float4 qv = *(const float4*)(qr + d0);
        float4 mv = *(const float4*)(mean + d0);
        anbuf[d0 + 0] = __fdiv_rn(__fmul_rn(qv.x, mv.x), nqd);
        anbuf[d0 + 1] = __fdiv_rn(__fmul_rn(qv.y, mv.y), nqd);
        anbuf[d0 + 2] = __fdiv_rn(__fmul_rn(qv.z, mv.z), nqd);
        anbuf[d0 + 3] = __fdiv_rn(__fmul_rn(qv.w, mv.w), nqd);
    }

    if (wave == 1) {
        float av = candv[(size_t)b * NCAND + lane];
        int aid = candi[(size_t)b * NCAND + lane];
        float t8;
        {
            float vv = av; int vid = aid;
            #pragma unroll
            for (int s = 0; s < TOPK; ++s) {
                float bv = vv; int bid = vid;
                #pragma unroll
                for (int off = 32; off >= 1; off >>= 1) {
                    float ov = __shfl_xor(bv, off);
                    int oid = __shfl_xor(bid, off);
                    if (ov > bv || (ov == bv && oid < bid)) { bv = ov; bid = oid; }
                }
                t8 = bv;
                if (vid == bid) vv = -1e30f;
            }
        }
        float thr = t8 - 0.003f * nqd;
        bool sel = (av >= thr);
        unsigned long long mk = __ballot(sel);
        int pos = __popcll(mk & ((1ull << lane) - 1ull));
        if (sel) selid[pos] = aid;
        if (lane == 0) m_s = (int)__popcll(mk);
    }
    __syncthreads();
    const int m = m_s;

    {
        const int s = tid >> 2, chunk = tid & 3;
        if (s < m) {
            const int id = selid[s];
            const int start = chunk * 320;
            const int n4 = (chunk == 3) ? 16 : 80;
            const float4* k4 = (const float4*)(knn + (size_t)id * D_DIM + start);
            const float4* a4 = (const float4*)(anbuf + start);
            float acc = 0.f;
            #pragma unroll 4
            for (int t = 0; t < n4; ++t) {
                float4 kv = k4[t];
                float4 av4 = a4[t];
                acc = __fmaf_rn(av4.x, kv.x, acc);
                acc = __fmaf_rn(av4.y, kv.y, acc);
                acc = __fmaf_rn(av4.z, kv.z, acc);
                acc = __fmaf_rn(av4.w, kv.w, acc);
            }
            float c2 = __shfl_down(acc, 1);
            float c3 = __shfl_down(acc, 2);
            float c4 = __shfl_down(acc, 3);
            if (chunk == 0) {
                vbuf[s] = __fadd_rn(__fadd_rn(__fadd_rn(acc, c2), c3), c4);
                ibuf[s] = id;
            }
        }
    }
    __syncthreads();

    if (wave == 0) {
        float v = (lane < m) ? vbuf[lane] : -3e38f;
        int id = (lane < m) ? ibuf[lane] : 0x7fffffff;
        float sv[TOPK]; int si[TOPK];
        #pragma unroll
        for (int s = 0; s < TOPK; ++s) {
            float bv = v; int bid = id;
            #pragma unroll
            for (int off = 32; off >= 1; off >>= 1) {
                float ov = __shfl_xor(bv, off);
                int oid = __shfl_xor(bid, off);
                if (ov > bv || (ov == bv && oid < bid)) { bv = ov; bid = oid; }
            }
            sv[s] = bv; si[s] = bid;
            if (id == bid) v = -3e38f;
        }
        if (lane == 0) {
            float mx = sv[0];
            float w[TOPK];
            float ssum = 0.f;
            #pragma unroll
            for (int k = 0; k < TOPK; ++k) { w[k] = expf(sv[k] - mx); ssum += w[k]; }
            float rs = 1.0f / ssum;
            #pragma unroll
            for (int k = 0; k < TOPK; ++k) {
                topw[b * TOPK + k] = w[k] * rs;
                topi[b * TOPK + k] = si[k];
            }
        }
    }
}

// ---------------- kernel F: weighted gather + outputs (nt stores) -----------
__global__ void output_kernel(const float* __restrict__ topw,
                              const int* __restrict__ topi,
                              const float* __restrict__ prompts,
                              const float* __restrict__ keys,
                              float* __restrict__ out) {
    int b = blockIdx.x;
    float w[TOPK];
    int id[TOPK];
    #pragma unroll
    for (int k = 0; k < TOPK; ++k) {
        w[k] = topw[b * TOPK + k];
        id[k] = topi[b * TOPK + k];
    }

    const size_t OFF1 = (size_t)B_ROWS * D_DIM;
    const size_t OFF2 = OFF1 + (size_t)B_ROWS * TOPK;

    if (threadIdx.x < TOPK)
        out[OFF1 + (size_t)b * TOPK + threadIdx.x] = (float)id[threadIdx.x];

    int d0 = threadIdx.x * 4;
    float4 acc; acc.x = acc.y = acc.z = acc.w = 0.f;
    #pragma unroll
    for (int k = 0; k < TOPK; ++k) {
        const float* pr = prompts + (size_t)id[k] * D_DIM + d0;
        float4 pv = *(const float4*)pr;
        acc.x += w[k] * pv.x; acc.y += w[k] * pv.y;
        acc.z += w[k] * pv.z; acc.w += w[k] * pv.w;
        const float* kr = keys + (size_t)id[k] * D_DIM + d0;
        float4 kv = *(const float4*)kr;
        nt_store4(kv, out + OFF2 + ((size_t)b * TOPK + k) * D_DIM + d0);
    }
    nt_store4(acc, out + (size_t)b * D_DIM + d0);
}

// ---------------- launch ----------------
extern "C" void kernel_launch(void* const* d_in, const int* in_sizes, int n_in,
                              void* d_out, int out_size, void* d_ws, size_t ws_size,
                              hipStream_t stream) {
    const float* query   = (const float*)d_in[0];
    const float* prompts = (const float*)d_in[1];
    const float* keys    = (const float*)d_in[2];
    const float* attn    = (const float*)d_in[3];
    float* ws = (float*)d_ws;
    float* out = (float*)d_out;

    float* mean  = ws + WS_MEAN;
    float* knorm = ws + WS_KNORM;
    float* knn   = ws + WS_KNN;
    unsigned short* kn16 = (unsigned short*)(ws + WS_KN16);
    int*   candi = (int*)(ws + WS_CI);
    float* topw  = ws + WS_TW;
    int*   topi  = (int*)(ws + WS_TI);
    float* outscratch = out + (size_t)B_ROWS * D_DIM + (size_t)B_ROWS * TOPK;
    unsigned short* aq16 = (unsigned short*)outscratch;
    float* candv = outscratch + 8388608;

    seqmean_kernel<<<16, 256, 0, stream>>>(attn, mean);
    knorm_kernel<<<N_COMP / 4, 256, 0, stream>>>(keys, knorm);
    knn_kernel<<<N_COMP, 256, 0, stream>>>(keys, knorm, knn, kn16);
    aq16_kernel<<<8192, 256, 0, stream>>>(query, mean, aq16);
    simtop_mfma<<<512, 512, 0, stream>>>(aq16, kn16, candi, candv);
    rescore_kernel<<<B_ROWS, 256, 0, stream>>>(query, knn, mean, candi, candv,
                                               topw, topi);
    output_kernel<<<B_ROWS, 256, 0, stream>>>(topw, topi, prompts, keys, out);
}

// Round 20
// 898.321 us; speedup vs baseline: 1.1261x; 1.0094x over previous
//
#include <hip/hip_runtime.h>
#include <math.h>

#define D_DIM 1024
#define N_COMP 4096
#define B_ROWS 16384
#define TOPK 8
#define NC_Q 16
#define NCAND 64
#define EPSV 1e-8f

typedef __bf16 bf16x8 __attribute__((ext_vector_type(8)));
typedef float f32x4 __attribute__((ext_vector_type(4)));

// ---------------- workspace layout (in float slots) ----------------
#define WS_MEAN  0         // 1024
#define WS_KNORM 1024      // 4096
#define WS_KNN   5120      // 4096*1024 f32 (bit-exact k_n, rescore input)
#define WS_KN16  4199424   // 4096*1024 bf16 (ushort) = 2097152 float slots
#define WS_CI    6296576   // packed candidates: 16384*64 ints (id<<16 | bf16 val)

__device__ __forceinline__ unsigned short bf16rne(float f) {
    unsigned int u = __float_as_uint(f);
    return (unsigned short)((u + 0x7FFFu + ((u >> 16) & 1u)) >> 16);
}

__device__ __forceinline__ void gload16(const void* g, void* l) {
    __builtin_amdgcn_global_load_lds(
        (const __attribute__((address_space(1))) void*)g,
        (__attribute__((address_space(3))) void*)l, 16, 0, 0);
}

__device__ __forceinline__ void nt_store4(const float4& v, float* p) {
    f32x4 x;
    x[0] = v.x; x[1] = v.y; x[2] = v.z; x[3] = v.w;
    __builtin_nontemporal_store(x, (f32x4*)p);
}

// ---------------- kernel A: np-faithful mean via LDS transpose --------------
__global__ void seqmean_kernel(const float* __restrict__ attn,
                               float* __restrict__ mean) {
    __shared__ float tile[128][65];
    const int tid = threadIdx.x;
    const int d0 = blockIdx.x * 64;
    const int c = tid & 63, r0 = tid >> 6;
    float acc = 0.f;
    for (int chunk = 0; chunk < 32; ++chunk) {
        const int base = chunk * 128;
        __syncthreads();
        #pragma unroll
        for (int rr = 0; rr < 32; ++rr) {
            int r = r0 * 32 + rr;
            tile[r][c] = attn[(size_t)(base + r) * D_DIM + d0 + c];
        }
        __syncthreads();
        if (tid < 64) {
            #pragma unroll 8
            for (int r = 0; r < 128; ++r)
                acc = __fadd_rn(acc, tile[r][tid]);
        }
    }
    if (tid < 64) mean[d0 + tid] = __fdiv_rn(acc, (float)N_COMP);
}

// ---------------- kernel B: np-faithful key norms, lane-parallel tree -------
__global__ void knorm_kernel(const float* __restrict__ keys,
                             float* __restrict__ knorm) {
    const int wave = threadIdx.x >> 6, lane = threadIdx.x & 63;
    const int n = blockIdx.x * 4 + wave;
    const float* x = keys + (size_t)n * D_DIM;
    const int l = lane & 15, g = lane >> 4;
    float lv0, lv1;
    {
        const float* xx = x + g * 128;
        float p[8];
        #pragma unroll
        for (int j = 0; j < 8; ++j) {
            float e = xx[16 * j + l];
            p[j] = __fmul_rn(e, e);
        }
        float t0 = __fadd_rn(p[0], p[1]), t1 = __fadd_rn(p[2], p[3]);
        float t2 = __fadd_rn(p[4], p[5]), t3 = __fadd_rn(p[6], p[7]);
        lv0 = __fadd_rn(__fadd_rn(t0, t1), __fadd_rn(t2, t3));
    }
    {
        const float* xx = x + (g + 4) * 128;
        float p[8];
        #pragma unroll
        for (int j = 0; j < 8; ++j) {
            float e = xx[16 * j + l];
            p[j] = __fmul_rn(e, e);
        }
        float t0 = __fadd_rn(p[0], p[1]), t1 = __fadd_rn(p[2], p[3]);
        float t2 = __fadd_rn(p[4], p[5]), t3 = __fadd_rn(p[6], p[7]);
        lv1 = __fadd_rn(__fadd_rn(t0, t1), __fadd_rn(t2, t3));
    }
    #pragma unroll
    for (int off = 8; off >= 1; off >>= 1) {
        lv0 = __fadd_rn(lv0, __shfl_down(lv0, off));
        lv1 = __fadd_rn(lv1, __shfl_down(lv1, off));
    }
    float L0 = __shfl(lv0, 0),  L1 = __shfl(lv0, 16),
          L2 = __shfl(lv0, 32), L3 = __shfl(lv0, 48);
    float L4 = __shfl(lv1, 0),  L5 = __shfl(lv1, 16),
          L6 = __shfl(lv1, 32), L7 = __shfl(lv1, 48);
    if (lane == 0) {
        float nk = __fadd_rn(
            __fadd_rn(__fadd_rn(L0, L1), __fadd_rn(L2, L3)),
            __fadd_rn(__fadd_rn(L4, L5), __fadd_rn(L6, L7)));
        knorm[n] = fmaxf(__fsqrt_rn(nk), EPSV);
    }
}

// ---------------- kernel C: knn f32 (frozen bits) + bf16 copy ---------------
__global__ void knn_kernel(const float* __restrict__ keys,
                           const float* __restrict__ knorm,
                           float* __restrict__ knn,
                           unsigned short* __restrict__ kn16) {
    int n = blockIdx.x;
    float kn = knorm[n];
    int d = threadIdx.x * 4;
    const float* row = keys + (size_t)n * D_DIM + d;
    float* orow = knn + (size_t)n * D_DIM + d;
    unsigned short* o16 = kn16 + (size_t)n * D_DIM + d;
    float r0 = __fdiv_rn(row[0], kn);
    float r1 = __fdiv_rn(row[1], kn);
    float r2 = __fdiv_rn(row[2], kn);
    float r3 = __fdiv_rn(row[3], kn);
    orow[0] = r0; orow[1] = r1; orow[2] = r2; orow[3] = r3;
    o16[0] = bf16rne(r0); o16[1] = bf16rne(r1);
    o16[2] = bf16rne(r2); o16[3] = bf16rne(r3);
}

// ---------------- kernel C2: aq16 = bf16(q * mean), precomputed -------------
__global__ void aq16_kernel(const float* __restrict__ q,
                            const float* __restrict__ mean,
                            unsigned short* __restrict__ aq16) {
    size_t i = ((size_t)blockIdx.x * 256 + threadIdx.x) * 8;
    int d = (int)(i & (D_DIM - 1));
    float4 a0 = *(const float4*)(q + i);
    float4 a1 = *(const float4*)(q + i + 4);
    float4 m0 = *(const float4*)(mean + d);
    float4 m1 = *(const float4*)(mean + d + 4);
    uint4 pk;
    pk.x = (unsigned)bf16rne(a0.x * m0.x) | ((unsigned)bf16rne(a0.y * m0.y) << 16);
    pk.y = (unsigned)bf16rne(a0.z * m0.z) | ((unsigned)bf16rne(a0.w * m0.w) << 16);
    pk.z = (unsigned)bf16rne(a1.x * m1.x) | ((unsigned)bf16rne(a1.y * m1.y) << 16);
    pk.w = (unsigned)bf16rne(a1.z * m1.z) | ((unsigned)bf16rne(a1.w * m1.w) << 16);
    *(uint4*)(aq16 + i) = pk;
}

// ---------------- kernel D: MFMA bf16 GEMM + per-quarter top-16 -------------
// R11/R15-exact structure (profiled 481 us). Only change: merge writes
// packed (id<<16 | bf16(value)) candidates — removes the candv buffer.
__global__ __launch_bounds__(512, 4) void simtop_mfma(
    const unsigned short* __restrict__ aq16,
    const unsigned short* __restrict__ kn16,
    int* __restrict__ candi) {
    __shared__ __align__(16) char RAW[49152];
    uint4* A4 = (uint4*)RAW;               // [128 rows][8 slots] 16KB
    uint4* B4 = (uint4*)(RAW + 16384);     // [256 cols][8 slots] 32KB
    float* SIM = (float*)RAW;              // [64][129] overlay (epilogue)
    float* VM  = (float*)RAW;              // [256][16] overlay (merge)
    int*   IM  = (int*)(RAW + 16384);      // [256][16]

    const int tid = threadIdx.x;
    const int lane = tid & 63;
    const int wid = tid >> 6;
    const int wr = wid >> 2, wc = wid & 3;
    const int l15 = lane & 15, l4 = lane >> 4;
    const int rb = blockIdx.x >> 2;
    const int qq = blockIdx.x & 3;
    const int row0 = rb * 128;
    const int colQ = qq * 1024;
    const int srow = tid & 127;
    const int sstripe = (tid >> 7) & 1;

    float v[NC_Q]; int ix[NC_Q];
    #pragma unroll
    for (int s = 0; s < NC_Q; ++s) { v[s] = -1e30f; ix[s] = 0; }

    for (int ct = 0; ct < 4; ++ct) {
        const int col0 = colQ + ct * 256;
        f32x4 acc[4][4];
        #pragma unroll
        for (int i = 0; i < 4; ++i)
            #pragma unroll
            for (int j = 0; j < 4; ++j) {
                acc[i][j][0] = 0.f; acc[i][j][1] = 0.f;
                acc[i][j][2] = 0.f; acc[i][j][3] = 0.f;
            }

        for (int kt = 0; kt < 16; ++kt) {
            const int k0 = kt * 64;
            __syncthreads();
            #pragma unroll
            for (int c = 0; c < 2; ++c) {
                int unit = c * 512 + tid;
                int r = unit >> 3, j = unit & 7;
                gload16(aq16 + (size_t)(row0 + r) * D_DIM + k0 + (j ^ (r & 7)) * 8,
                        (char*)A4 + unit * 16);
            }
            #pragma unroll
            for (int c = 0; c < 4; ++c) {
                int unit = c * 512 + tid;
                int r = unit >> 3, j = unit & 7;
                gload16(kn16 + (size_t)(col0 + r) * D_DIM + k0 + (j ^ (r & 7)) * 8,
                        (char*)B4 + unit * 16);
            }
            __syncthreads();
            #pragma unroll
            for (int kk = 0; kk < 2; ++kk) {
                bf16x8 af[4], bfv[4];
                #pragma unroll
                for (int f = 0; f < 4; ++f) {
                    int rowa = wr * 64 + f * 16 + l15;
                    int slot = kk * 4 + l4;
                    af[f] = __builtin_bit_cast(bf16x8,
                              A4[rowa * 8 + (slot ^ (rowa & 7))]);
                    int rowb = wc * 64 + f * 16 + l15;
                    bfv[f] = __builtin_bit_cast(bf16x8,
                              B4[rowb * 8 + (slot ^ (rowb & 7))]);
                }
                #pragma unroll
                for (int i = 0; i < 4; ++i)
                    #pragma unroll
                    for (int j = 0; j < 4; ++j)
                        acc[i][j] = __builtin_amdgcn_mfma_f32_16x16x32_bf16(
                            af[i], bfv[j], acc[i][j], 0, 0, 0);
            }
        }
        #pragma unroll 1
        for (int p = 0; p < 4; ++p) {
            __syncthreads();
            if (wr == (p >> 1) && (wc >> 1) == (p & 1)) {
                #pragma unroll
                for (int i = 0; i < 4; ++i)
                    #pragma unroll
                    for (int j = 0; j < 4; ++j)
                        #pragma unroll
                        for (int rg = 0; rg < 4; ++rg)
                            SIM[(i * 16 + l4 * 4 + rg) * 129 +
                                (wc & 1) * 64 + j * 16 + l15] = acc[i][j][rg];
            }
            __syncthreads();
            if (tid < 256 && (srow >> 6) == (p >> 1)) {
                const float* rp = SIM + (srow & 63) * 129 + sstripe * 64;
                const int gbase = col0 + (p & 1) * 128 + sstripe * 64;
                #pragma unroll 1
                for (int cc = 0; cc < 64; ++cc) {
                    float cv = rp[cc];
                    if (cv > v[NC_Q - 1]) {
                        v[NC_Q - 1] = cv; ix[NC_Q - 1] = gbase + cc;
                        #pragma unroll
                        for (int s = NC_Q - 1; s > 0; --s)
                            if (v[s] > v[s - 1]) {
                                float tv = v[s]; v[s] = v[s - 1]; v[s - 1] = tv;
                                int ti = ix[s]; ix[s] = ix[s - 1]; ix[s - 1] = ti;
                            }
                    }
                }
            }
        }
    }
    __syncthreads();
    if (tid < 256) {
        #pragma unroll
        for (int s = 0; s < NC_Q; ++s) {
            VM[tid * 16 + s] = v[s];
            IM[tid * 16 + s] = ix[s];
        }
    }
    __syncthreads();
    if (tid < 128) {
        int ia = 0, ib = 0;
        size_t obase = (size_t)(row0 + tid) * NCAND + qq * 16;
        #pragma unroll 1
        for (int s = 0; s < NC_Q; ++s) {
            float va = (ia < 16) ? VM[tid * 16 + ia] : -3e38f;
            float vb = (ib < 16) ? VM[(tid + 128) * 16 + ib] : -3e38f;
            int id; float vv;
            if (va >= vb) { id = IM[tid * 16 + ia]; vv = va; ++ia; }
            else          { id = IM[(tid + 128) * 16 + ib]; vv = vb; ++ib; }
            candi[obase + s] = (id << 16) | (int)bf16rne(vv);
        }
    }
}

// ---------------- kernel E: fused sparse rescore + output -------------------
// Rescore math bit-identical to the R15-passed version; candidate values
// decoded from packed bf16 (selection threshold widened 0.003 -> 0.004 to
// absorb quantization). Output phase appended via LDS handoff.
__global__ __launch_bounds__(256) void rescore_output_kernel(
    const float* __restrict__ q, const float* __restrict__ knn,
    const float* __restrict__ mean, const int* __restrict__ candi,
    const float* __restrict__ prompts, const float* __restrict__ keys,
    float* __restrict__ out) {
    __shared__ float anbuf[D_DIM];
    __shared__ float vbuf[NCAND];
    __shared__ int ibuf[NCAND];
    __shared__ int selid[NCAND];
    __shared__ float snq;
    __shared__ int m_s;
    __shared__ float sw[TOPK];
    __shared__ int sid[TOPK];
    const int tid = threadIdx.x;
    const int wave = tid >> 6, lane = tid & 63;
    const int b = blockIdx.x;
    const float* qr = q + (size_t)b * D_DIM;

    // ---- wave 0: numpy pairwise norm tree (frozen bits) ----
    if (wave == 0) {
        const int l = lane & 15, g = lane >> 4;
        float lv0, lv1;
        {
            const float* x = qr + g * 128;
            const float* m = mean + g * 128;
            float p[8];
            #pragma unroll
            for (int j = 0; j < 8; ++j) {
                float e = __fmul_rn(x[16 * j + l], m[16 * j + l]);
                p[j] = __fmul_rn(e, e);
            }
            float t0 = __fadd_rn(p[0], p[1]), t1 = __fadd_rn(p[2], p[3]);
            float t2 = __fadd_rn(p[4], p[5]), t3 = __fadd_rn(p[6], p[7]);
            lv0 = __fadd_rn(__fadd_rn(t0, t1), __fadd_rn(t2, t3));
        }
        {
            const float* x = qr + (g + 4) * 128;
            const float* m = mean + (g + 4) * 128;
            float p[8];
            #pragma unroll
            for (int j = 0; j < 8; ++j) {
                float e = __fmul_rn(x[16 * j + l], m[16 * j + l]);
                p[j] = __fmul_rn(e, e);
            }
            float t0 = __fadd_rn(p[0], p[1]), t1 = __fadd_rn(p[2], p[3]);
            float t2 = __fadd_rn(p[4], p[5]), t3 = __fadd_rn(p[6], p[7]);
            lv1 = __fadd_rn(__fadd_rn(t0, t1), __fadd_rn(t2, t3));
        }
        #pragma unroll
        for (int off = 8; off >= 1; off >>= 1) {
            lv0 = __fadd_rn(lv0, __shfl_down(lv0, off));
            lv1 = __fadd_rn(lv1, __shfl_down(lv1, off));
        }
        float L0 = __shfl(lv0, 0),  L1 = __shfl(lv0, 16),
              L2 = __shfl(lv0, 32), L3 = __shfl(lv0, 48);
        float L4 = __shfl(lv1, 0),  L5 = __shfl(lv1, 16),
              L6 = __shfl(lv1, 32), L7 = __shfl(lv1, 48);
        if (lane == 0) {
            float nq = __fadd_rn(
                __fadd_rn(__fadd_rn(L0, L1), __fadd_rn(L2, L3)),
                __fadd_rn(__fadd_rn(L4, L5), __fadd_rn(L6, L7)));
            snq = fmaxf(__fsqrt_rn(nq), EPSV);
        }
    }
    __syncthreads();
    const float nqd = snq;

    // ---- all threads: materialize f32 aq_n (frozen bits) ----
    {
        int d0 = tid * 4;
        float4 qv = *(const float4*)(qr + d0);
        float4 mv = *(const float4*)(mean + d0);
        anbuf[d0 + 0] = __fdiv_rn(__fmul_rn(qv.x, mv.x), nqd);
        anbuf[d0 + 1] = __fdiv_rn(__fmul_rn(qv.y, mv.y), nqd);
        anbuf[d0 + 2] = __fdiv_rn(__fmul_rn(qv.z, mv.z), nqd);
        anbuf[d0 + 3] = __fdiv_rn(__fmul_rn(qv.w, mv.w), nqd);
    }

    // ---- wave 1: approx t8 + threshold selection (packed candidates) ----
    if (wave == 1) {
        int pk = candi[(size_t)b * NCAND + lane];
        int aid = (int)(((unsigned)pk) >> 16);
        float av = __uint_as_float(((unsigned)pk & 0xFFFFu) << 16);
        float t8;
        {
            float vv = av; int vid = aid;
            #pragma unroll
            for (int s = 0; s < TOPK; ++s) {
                float bv = vv; int bid = vid;
                #pragma unroll
                for (int off = 32; off >= 1; off >>= 1) {
                    float ov = __shfl_xor(bv, off);
                    int oid = __shfl_xor(bid, off);
                    if (ov > bv || (ov == bv && oid < bid)) { bv = ov; bid = oid; }
                }
                t8 = bv;
                if (vid == bid) vv = -1e30f;
            }
        }
        float thr = t8 - 0.004f * nqd;
        bool sel = (av >= thr);
        unsigned long long mk = __ballot(sel);
        int pos = __popcll(mk & ((1ull << lane) - 1ull));
        if (sel) selid[pos] = aid;
        if (lane == 0) m_s = (int)__popcll(mk);
    }
    __syncthreads();
    const int m = m_s;

    // ---- sparse exact rescore: tid = s*4 + chunk, s < m (frozen math) ----
    {
        const int s = tid >> 2, chunk = tid & 3;
        if (s < m) {
            const int id = selid[s];
            const int start = chunk * 320;
            const int n4 = (chunk == 3) ? 16 : 80;
            const float4* k4 = (const float4*)(knn + (size_t)id * D_DIM + start);
            const float4* a4 = (const float4*)(anbuf + start);
            float acc = 0.f;
            #pragma unroll 4
            for (int t = 0; t < n4; ++t) {
                float4 kv = k4[t];
                float4 av4 = a4[t];
                acc = __fmaf_rn(av4.x, kv.x, acc);
                acc = __fmaf_rn(av4.y, kv.y, acc);
                acc = __fmaf_rn(av4.z, kv.z, acc);
                acc = __fmaf_rn(av4.w, kv.w, acc);
            }
            float c2 = __shfl_down(acc, 1);
            float c3 = __shfl_down(acc, 2);
            float c4 = __shfl_down(acc, 3);
            if (chunk == 0) {
                vbuf[s] = __fadd_rn(__fadd_rn(__fadd_rn(acc, c2), c3), c4);
                ibuf[s] = id;
            }
        }
    }
    __syncthreads();

    // ---- wave 0: exact top-8 knockout + softmax -> LDS handoff ----
    if (wave == 0) {
        float v = (lane < m) ? vbuf[lane] : -3e38f;
        int id = (lane < m) ? ibuf[lane] : 0x7fffffff;
        float sv[TOPK]; int si[TOPK];
        #pragma unroll
        for (int s = 0; s < TOPK; ++s) {
            float bv = v; int bid = id;
            #pragma unroll
            for (int off = 32; off >= 1; off >>= 1) {
                float ov = __shfl_xor(bv, off);
                int oid = __shfl_xor(bid, off);
                if (ov > bv || (ov == bv && oid < bid)) { bv = ov; bid = oid; }
            }
            sv[s] = bv; si[s] = bid;
            if (id == bid) v = -3e38f;
        }
        if (lane == 0) {
            float mx = sv[0];
            float w[TOPK];
            float ssum = 0.f;
            #pragma unroll
            for (int k = 0; k < TOPK; ++k) { w[k] = expf(sv[k] - mx); ssum += w[k]; }
            float rs = 1.0f / ssum;
            #pragma unroll
            for (int k = 0; k < TOPK; ++k) {
                sw[k] = w[k] * rs;
                sid[k] = si[k];
            }
        }
    }
    __syncthreads();

    // ---- output phase (frozen body, weights/ids from LDS) ----
    float w[TOPK];
    int id[TOPK];
    #pragma unroll
    for (int k = 0; k < TOPK; ++k) {
        w[k] = sw[k];
        id[k] = sid[k];
    }

    const size_t OFF1 = (size_t)B_ROWS * D_DIM;
    const size_t OFF2 = OFF1 + (size_t)B_ROWS * TOPK;

    if (tid < TOPK)
        out[OFF1 + (size_t)b * TOPK + tid] = (float)id[tid];

    int d0 = tid * 4;
    float4 acc; acc.x = acc.y = acc.z = acc.w = 0.f;
    #pragma unroll
    for (int k = 0; k < TOPK; ++k) {
        const float* pr = prompts + (size_t)id[k] * D_DIM + d0;
        float4 pv = *(const float4*)pr;
        acc.x += w[k] * pv.x; acc.y += w[k] * pv.y;
        acc.z += w[k] * pv.z; acc.w += w[k] * pv.w;
        const float* kr = keys + (size_t)id[k] * D_DIM + d0;
        float4 kv = *(const float4*)kr;
        nt_store4(kv, out + OFF2 + ((size_t)b * TOPK + k) * D_DIM + d0);
    }
    nt_store4(acc, out + (size_t)b * D_DIM + d0);
}

// ---------------- launch ----------------
extern "C" void kernel_launch(void* const* d_in, const int* in_sizes, int n_in,
                              void* d_out, int out_size, void* d_ws, size_t ws_size,
                              hipStream_t stream) {
    const float* query   = (const float*)d_in[0];
    const float* prompts = (const float*)d_in[1];
    const float* keys    = (const float*)d_in[2];
    const float* attn    = (const float*)d_in[3];
    float* ws = (float*)d_ws;
    float* out = (float*)d_out;

    float* mean  = ws + WS_MEAN;
    float* knorm = ws + WS_KNORM;
    float* knn   = ws + WS_KNN;
    unsigned short* kn16 = (unsigned short*)(ws + WS_KN16);
    int*   candi = (int*)(ws + WS_CI);
    // aq16 scratch in the selected_keys output region (dead after simtop;
    // overwritten by the fused kernel's output phase afterwards).
    float* outscratch = out + (size_t)B_ROWS * D_DIM + (size_t)B_ROWS * TOPK;
    unsigned short* aq16 = (unsigned short*)outscratch;

    seqmean_kernel<<<16, 256, 0, stream>>>(attn, mean);
    knorm_kernel<<<N_COMP / 4, 256, 0, stream>>>(keys, knorm);
    knn_kernel<<<N_COMP, 256, 0, stream>>>(keys, knorm, knn, kn16);
    aq16_kernel<<<8192, 256, 0, stream>>>(query, mean, aq16);
    simtop_mfma<<<512, 512, 0, stream>>>(aq16, kn16, candi);
    rescore_output_kernel<<<B_ROWS, 256, 0, stream>>>(query, knn, mean, candi,
                                                      prompts, keys, out);
}